// Round 13
// baseline (267.713 us; speedup 1.0000x reference)
//
#include <hip/hip_runtime.h>

#define DIM   128
#define DMASK 127
#define PLANE (DIM * DIM)     // 16384
#define VOX   (1 << 21)       // 128^3
#define NCH   12

// De-aliased layout (validated r12: 199->142 us): channel stride 4MB+4KB,
// image stride +2KB more. Keeps the 24 stream bases off one channel slot.
#define CHS   (VOX + 2048)
#define IMGS  (NCH * CHS + 1024)

typedef __attribute__((ext_vector_type(2))) _Float16 half2v;
typedef __attribute__((ext_vector_type(4))) _Float16 half4v;

// Per-channel shift pairs (d,h,w) = 2*(one_hot_idx - 1); verified (absmax 0).
__constant__ int c_sd1[12] = { 0, 0, 0, 0, 0, 2, 2, 2, 0, 0, 0, 0};
__constant__ int c_sh1[12] = { 0,-2,-2, 0, 0, 0, 0, 0, 2, 2, 2, 2};
__constant__ int c_sw1[12] = {-2, 0, 0, 2, 2, 0, 0, 0, 0, 0, 0, 0};
__constant__ int c_sd2[12] = {-2,-2, 0,-2, 0, 0, 0, 0,-2, 0, 0, 2};
__constant__ int c_sh2[12] = { 0, 0, 0, 0,-2, 0,-2, 0, 0, 0, 0, 0};
__constant__ int c_sw2[12] = { 0, 0,-2, 0, 0,-2, 0, 2, 0,-2, 2, 0};

__device__ __forceinline__ int clamp7(int v) { return min(max(v, 0), DMASK); }

// F123 v3: diff^2 + W-box fused in registers (per-lane precomputed clamped
// column offsets), H-box + D-box as before. T1 double-buffered fp16 ->
// exactly ONE __syncthreads per plane (was 2; r12 showed barrier stalls
// dominate: VALUBusy 39% vs 26% occupancy at 3 blocks/CU).
__global__ __launch_bounds__(256) void f123(const float* __restrict__ img0,
                                            const float* __restrict__ img1,
                                            _Float16* __restrict__ Sall) {
    const float* img = blockIdx.y ? img1 : img0;
    _Float16* outS = Sall + (size_t)blockIdx.y * IMGS;

    int b  = blockIdx.x;            // 384 = 12 ch * 4 hq * 8 dseg
    int ch = b >> 5;
    int hq = (b >> 3) & 3;
    int ds = b & 7;
    int h0 = hq << 5;
    int d0 = ds << 4;
    int tid = threadIdx.x;

    __shared__ int rowA[36], rowB[36];
    __shared__ __align__(16) _Float16 T1[2][36 * 128];   // 18 KB dbuf

    int sd1 = c_sd1[ch], sh1 = c_sh1[ch], sw1 = c_sw1[ch];
    int sd2 = c_sd2[ch], sh2 = c_sh2[ch], sw2 = c_sw2[ch];

    if (tid < 36) {
        int hqr = clamp7(h0 - 2 + tid);
        rowA[tid] = clamp7(hqr + sh1) * (DIM * 4);
        rowB[tid] = clamp7(hqr + sh2) * (DIM * 4);
    }

    int l  = tid & 63;              // column pair 2l,2l+1 (fixed)
    int rq = tid >> 6;
    int wp  = l << 1;               // phase3 column pair (same cols)
    int lh0 = rq << 3;              // phase3 first of 8 rows

    // per-lane double-clamped column byte offsets for the 6 D2 cols
    int offA[6], offB[6];
#pragma unroll
    for (int e = 0; e < 6; ++e) {
        int wb = clamp7((l << 1) - 2 + e);   // box-pad clamp
        offA[e] = clamp7(wb + sw1) * 4;      // shift clamp
        offB[e] = clamp7(wb + sw2) * 4;
    }

    float2 win[8];
    half2v hist[5][8];
#pragma unroll
    for (int k = 0; k < 8; ++k) {
        win[k].x = 0.0f; win[k].y = 0.0f;
#pragma unroll
        for (int s = 0; s < 5; ++s) hist[s][k] = half2v{(_Float16)0.0f, (_Float16)0.0f};
    }

    _Float16* dstBase = outS + (size_t)ch * CHS + (h0 + lh0) * DIM + wp;

    __syncthreads();                // rowA/rowB ready

    for (int oo = 0; oo < 4; ++oo) {
#pragma unroll
        for (int s = 0; s < 5; ++s) {
            int it = oo * 5 + s;
            int dp = clamp7(d0 - 2 + it);
            const char* pA = (const char*)(img + clamp7(dp + sd1) * PLANE);
            const char* pB = (const char*)(img + clamp7(dp + sd2) * PLANE);
            _Float16* Tc = T1[it & 1];

            // phase A: diff^2 + W-box in registers, fp16 T1 write
#pragma unroll
            for (int k = 0; k < 9; ++k) {
                int r = rq + (k << 2);       // 36 rows
                const char* ra = pA + rowA[r];
                const char* rb = pB + rowB[r];
                float dd[6];
#pragma unroll
                for (int e = 0; e < 6; ++e) {
                    float a = *(const float*)(ra + offA[e]);
                    float c = *(const float*)(rb + offB[e]);
                    float df = a - c;
                    dd[e] = df * df;
                }
                float o0 = dd[0] + dd[1] + dd[2] + dd[3] + dd[4];
                float o1 = o0 - dd[0] + dd[5];
                half2v hv = { (_Float16)o0, (_Float16)o1 };
                *(half2v*)&Tc[r * 128 + (l << 1)] = hv;
            }
            __syncthreads();                 // the ONE barrier per plane

            // phase 3: H-box (sliding 5-row col sums) -> D-window -> store
            {
                const _Float16* base = &Tc[lh0 * 128 + wp];
                float rx[12], ry[12];
#pragma unroll
                for (int k = 0; k < 12; ++k) {
                    half2v v = *(const half2v*)(base + k * 128);
                    rx[k] = (float)v[0]; ry[k] = (float)v[1];
                }
                float sx = rx[0] + rx[1] + rx[2] + rx[3] + rx[4];
                float sy = ry[0] + ry[1] + ry[2] + ry[3] + ry[4];
                bool dowrite = (it >= 4);
                _Float16* dstD = dstBase + (size_t)(d0 + it - 4) * PLANE;
#pragma unroll
                for (int k = 0; k < 8; ++k) {
                    half2v hv = { (_Float16)sx, (_Float16)sy };  // round first
                    half2v old = hist[s][k];
                    win[k].x += (float)hv[0] - (float)old[0];
                    win[k].y += (float)hv[1] - (float)old[1];
                    hist[s][k] = hv;
                    if (dowrite) {
                        half2v ov = { (_Float16)win[k].x, (_Float16)win[k].y };
                        *(half2v*)(dstD + k * DIM) = ov;
                    }
                    if (k < 7) {
                        sx += rx[k + 5] - rx[k];
                        sy += ry[k + 5] - ry[k];
                    }
                }
            }
            // no second sync: next plane writes T1[(it+1)&1]; a thread only
            // reaches the sync after ITS phase3 reads, so by the time any
            // thread writes buffer parity p again (two planes later, after
            // another sync) all readers of parity p are done.
        }
    }
}

// kmse v6 (unchanged, validated r12): 4 vox/thread, 24 independent 8-B
// loads, all-register, no atomics, de-aliased CHS stride.
__global__ __launch_bounds__(256, 3) void kmse(const _Float16* __restrict__ S0,
                                               const _Float16* __restrict__ S1,
                                               float* __restrict__ partial) {
    int t = blockIdx.x * 256 + threadIdx.x;       // 2048 blocks

    half4v v0[NCH], v1[NCH];
#pragma unroll
    for (int ch = 0; ch < NCH; ++ch)
        v0[ch] = ((const half4v*)(S0 + (size_t)ch * CHS))[t];
#pragma unroll
    for (int ch = 0; ch < NCH; ++ch)
        v1[ch] = ((const half4v*)(S1 + (size_t)ch * CHS))[t];

    float mn0[4], sm0[4], mn1[4], sm1[4];
#pragma unroll
    for (int j = 0; j < 4; ++j) {
        mn0[j] = 3.4e38f; sm0[j] = 0.0f;
        mn1[j] = 3.4e38f; sm1[j] = 0.0f;
    }
#pragma unroll
    for (int ch = 0; ch < NCH; ++ch)
#pragma unroll
        for (int j = 0; j < 4; ++j) {
            float s0 = (float)v0[ch][j];
            float s1 = (float)v1[ch][j];
            mn0[j] = fminf(mn0[j], s0); sm0[j] += s0;
            mn1[j] = fminf(mn1[j], s1); sm1[j] += s1;
        }

    float inv0[4], inv1[4];
#pragma unroll
    for (int j = 0; j < 4; ++j) {
        inv0[j] = __fdividef(1.0f, sm0[j] * (1.0f / 12.0f) - mn0[j]);
        inv1[j] = __fdividef(1.0f, sm1[j] * (1.0f / 12.0f) - mn1[j]);
    }

    float acc = 0.0f;
#pragma unroll
    for (int ch = 0; ch < NCH; ++ch)
#pragma unroll
        for (int j = 0; j < 4; ++j) {
            float e0 = __expf(-((float)v0[ch][j] - mn0[j]) * inv0[j]);
            float e1 = __expf(-((float)v1[ch][j] - mn1[j]) * inv1[j]);
            float df = e0 - e1;
            acc += df * df;
        }

#pragma unroll
    for (int off = 32; off > 0; off >>= 1)
        acc += __shfl_down(acc, off, 64);
    __shared__ float smem[4];
    int lane = threadIdx.x & 63, wv = threadIdx.x >> 6;
    if (lane == 0) smem[wv] = acc;
    __syncthreads();
    if (threadIdx.x == 0)
        partial[blockIdx.x] = smem[0] + smem[1] + smem[2] + smem[3];
}

// kred: sum 2048 partials, write the final scalar.
__global__ __launch_bounds__(256) void kred(const float* __restrict__ partial,
                                            float* __restrict__ out) {
    int tid = threadIdx.x;
    float acc = 0.0f;
#pragma unroll
    for (int k = 0; k < 8; ++k)
        acc += partial[tid + (k << 8)];
#pragma unroll
    for (int off = 32; off > 0; off >>= 1)
        acc += __shfl_down(acc, off, 64);
    __shared__ float smem[4];
    int lane = tid & 63, wv = tid >> 6;
    if (lane == 0) smem[wv] = acc;
    __syncthreads();
    if (tid == 0)
        out[0] = (smem[0] + smem[1] + smem[2] + smem[3])
               * (1.0f / (12.0f * (float)VOX));
}

__global__ void kdiag(float* out, float ws_mb) { out[0] = ws_mb; }

extern "C" void kernel_launch(void* const* d_in, const int* in_sizes, int n_in,
                              void* d_out, int out_size, void* d_ws, size_t ws_size,
                              hipStream_t stream) {
    const float* y_true = (const float*)d_in[0];
    const float* y_pred = (const float*)d_in[1];
    float* out = (float*)d_out;

    const size_t NEED = 2ull * IMGS * sizeof(_Float16) + 8192 + 64;  // ~96.2 MB
    if (ws_size < NEED) {
        kdiag<<<1, 1, 0, stream>>>(out, (float)(ws_size >> 20));
        return;
    }

    _Float16* S0      = (_Float16*)d_ws;            // ssd img0 (padded layout)
    _Float16* S1      = S0 + (size_t)IMGS;          // ssd img1
    float*    partial = (float*)(S1 + (size_t)IMGS);// 2048 floats

    f123<<<dim3(12 * 4 * 8, 2), 256, 0, stream>>>(y_true, y_pred, S0);
    kmse<<<VOX / 4 / 256, 256, 0, stream>>>(S0, S1, partial);
    kred<<<1, 256, 0, stream>>>(partial, out);
}

// Round 14
// 152.002 us; speedup vs baseline: 1.7612x; 1.7612x over previous
//
#include <hip/hip_runtime.h>

#define DIM   128
#define DMASK 127
#define PLANE (DIM * DIM)     // 16384
#define VOX   (1 << 21)       // 128^3
#define NCH   12

// De-aliased layout (validated r12: 199->142 us): channel stride 4MB+4KB,
// image stride +2KB more. Keeps the 24 stream bases off one channel slot.
#define CHS   (VOX + 2048)
#define IMGS  (NCH * CHS + 1024)

typedef __attribute__((ext_vector_type(2))) _Float16 half2v;
typedef __attribute__((ext_vector_type(4))) _Float16 half4v;

#define D2S 136

// Per-channel shift pairs (d,h,w) = 2*(one_hot_idx - 1); verified (absmax 0).
__constant__ int c_sd1[12] = { 0, 0, 0, 0, 0, 2, 2, 2, 0, 0, 0, 0};
__constant__ int c_sh1[12] = { 0,-2,-2, 0, 0, 0, 0, 0, 2, 2, 2, 2};
__constant__ int c_sw1[12] = {-2, 0, 0, 2, 2, 0, 0, 0, 0, 0, 0, 0};
__constant__ int c_sd2[12] = {-2,-2, 0,-2, 0, 0, 0, 0,-2, 0, 0, 2};
__constant__ int c_sh2[12] = { 0, 0, 0, 0,-2, 0,-2, 0, 0, 0, 0, 0};
__constant__ int c_sw2[12] = { 0, 0,-2, 0, 0,-2, 0, 2, 0,-2, 2, 0};

__device__ __forceinline__ int clamp7(int v) { return min(max(v, 0), DMASK); }

// F123 v4 = r12 structure (coalesced float2 phase1 -> fp16 D2p -> W-box ->
// T1 -> H-box sliding -> D-window), with:
//  - dseg 8 (grid 1536 -> 6 blocks/CU; r12 was grid-limited at 3)
//  - T1 fp16 (LDS ~19.3 KB; r13 validated these numerics)
//  - full 12-plane unroll so hist[it%5] stays statically indexed
__global__ __launch_bounds__(256) void f123(const float* __restrict__ img0,
                                            const float* __restrict__ img1,
                                            _Float16* __restrict__ Sall) {
    const float* img = blockIdx.y ? img1 : img0;
    _Float16* outS = Sall + (size_t)blockIdx.y * IMGS;

    int b  = blockIdx.x;            // 768 = 12 ch * 4 hq * 16 dseg
    int ch = b >> 6;
    int hq = (b >> 4) & 3;
    int ds = b & 15;
    int h0 = hq << 5;
    int d0 = ds << 3;               // 8 output planes per block
    int tid = threadIdx.x;

    __shared__ int rowA[36], rowB[36];
    __shared__ __align__(16) _Float16 D2p[36 * D2S];
    __shared__ __align__(16) _Float16 T1[36 * 128];

    int sd1 = c_sd1[ch], sh1 = c_sh1[ch], sw1 = c_sw1[ch];
    int sd2 = c_sd2[ch], sh2 = c_sh2[ch], sw2 = c_sw2[ch];

    if (tid < 36) {
        int hqr = clamp7(h0 - 2 + tid);
        rowA[tid] = clamp7(hqr + sh1) * (DIM * 4);
        rowB[tid] = clamp7(hqr + sh2) * (DIM * 4);
    }
    __syncthreads();

    int l  = tid & 63;              // phase1 interior lane
    int rr = tid >> 6;
    int wp  = (tid & 63) << 1;      // phase3: column pair
    int lh0 = (tid >> 6) << 3;      // phase3: first of 8 rows

    int cAi = 0, cBi = 0;
    if (l < 62) {
        int j0 = 4 + (l << 1);
        cAi = (j0 - 2 + sw1) * 4;
        cBi = (j0 - 2 + sw2) * 4;
    }

    float2 win[8];
    half2v hist[5][8];
#pragma unroll
    for (int k = 0; k < 8; ++k) {
        win[k].x = 0.0f; win[k].y = 0.0f;
#pragma unroll
        for (int s = 0; s < 5; ++s) hist[s][k] = half2v{(_Float16)0.0f, (_Float16)0.0f};
    }

    _Float16* dstBase = outS + (size_t)ch * CHS + (h0 + lh0) * DIM + wp;

#pragma unroll
    for (int it = 0; it < 12; ++it) {           // 8 outputs + 4 halo planes
        const int s = it % 5;                   // static hist slot
        int dp = clamp7(d0 - 2 + it);
        const char* pA = (const char*)(img + clamp7(dp + sd1) * PLANE);
        const char* pB = (const char*)(img + clamp7(dp + sd2) * PLANE);

        // phase 1 interior: coalesced unclamped float2 loads, j0 in [4,126]
        if (l < 62) {
            int j0 = 4 + (l << 1);
#pragma unroll
            for (int k = 0; k < 9; ++k) {
                int r = rr + (k << 2);
                float2 a = *(const float2*)(pA + rowA[r] + cAi);
                float2 c = *(const float2*)(pB + rowB[r] + cBi);
                float e0 = a.x - c.x, e1 = a.y - c.y;
                half2v hv = { (_Float16)(e0 * e0), (_Float16)(e1 * e1) };
                *(half2v*)&D2p[r * D2S + j0] = hv;
            }
        }
        // phase 1 edges: j0 in {0,2,128,130}, scalar double-clamp
        if (tid < 144) {
            int r  = tid >> 2;
            int pe = tid & 3;
            int j0 = (pe < 2) ? (pe << 1) : (124 + (pe << 1));
            int ra = rowA[r], rb = rowB[r];
            float dd[2];
#pragma unroll
            for (int e = 0; e < 2; ++e) {
                int wq = clamp7(j0 + e - 2);
                float a = *(const float*)(pA + ra + clamp7(wq + sw1) * 4);
                float c = *(const float*)(pB + rb + clamp7(wq + sw2) * 4);
                float df = a - c;
                dd[e] = df * df;
            }
            half2v hv = { (_Float16)dd[0], (_Float16)dd[1] };
            *(half2v*)&D2p[r * D2S + j0] = hv;
        }
        __syncthreads();

        // phase 2: W-box, 4 outputs/unit, fp16 T1
        for (int i = tid; i < 36 * 32; i += 256) {
            int r = i >> 5;
            int g = (i & 31) << 2;
            const half4v* src = (const half4v*)&D2p[r * D2S + g];
            half4v lo = src[0], hi = src[1];
            float l0 = lo[0], l1 = lo[1], l2 = lo[2], l3 = lo[3];
            float u0 = hi[0], u1 = hi[1], u2 = hi[2], u3 = hi[3];
            float o0 = l0 + l1 + l2 + l3 + u0;
            float o1 = o0 - l0 + u1;
            float o2 = o1 - l1 + u2;
            float o3 = o2 - l2 + u3;
            half4v ov = { (_Float16)o0, (_Float16)o1, (_Float16)o2, (_Float16)o3 };
            *(half4v*)&T1[r * 128 + g] = ov;
        }
        __syncthreads();

        // phase 3: H-box (sliding 5-row col sums) -> D-window update
        {
            const _Float16* base = &T1[lh0 * 128 + wp];
            float rx[12], ry[12];
#pragma unroll
            for (int k = 0; k < 12; ++k) {
                half2v v = *(const half2v*)(base + k * 128);
                rx[k] = (float)v[0]; ry[k] = (float)v[1];
            }
            float sx = rx[0] + rx[1] + rx[2] + rx[3] + rx[4];
            float sy = ry[0] + ry[1] + ry[2] + ry[3] + ry[4];
            bool dowrite = (it >= 4);
            _Float16* dstD = dstBase + (size_t)(d0 + it - 4) * PLANE;
#pragma unroll
            for (int k = 0; k < 8; ++k) {
                half2v hv = { (_Float16)sx, (_Float16)sy };  // round first
                half2v old = hist[s][k];
                win[k].x += (float)hv[0] - (float)old[0];
                win[k].y += (float)hv[1] - (float)old[1];
                hist[s][k] = hv;
                if (dowrite) {
                    half2v ov = { (_Float16)win[k].x, (_Float16)win[k].y };
                    *(half2v*)(dstD + k * DIM) = ov;
                }
                if (k < 7) {
                    sx += rx[k + 5] - rx[k];
                    sy += ry[k + 5] - ry[k];
                }
            }
        }
    }
}

// kmse v6 (unchanged, validated r12): 4 vox/thread, 24 independent 8-B
// loads, all-register, no atomics, de-aliased CHS stride.
__global__ __launch_bounds__(256, 3) void kmse(const _Float16* __restrict__ S0,
                                               const _Float16* __restrict__ S1,
                                               float* __restrict__ partial) {
    int t = blockIdx.x * 256 + threadIdx.x;       // 2048 blocks

    half4v v0[NCH], v1[NCH];
#pragma unroll
    for (int ch = 0; ch < NCH; ++ch)
        v0[ch] = ((const half4v*)(S0 + (size_t)ch * CHS))[t];
#pragma unroll
    for (int ch = 0; ch < NCH; ++ch)
        v1[ch] = ((const half4v*)(S1 + (size_t)ch * CHS))[t];

    float mn0[4], sm0[4], mn1[4], sm1[4];
#pragma unroll
    for (int j = 0; j < 4; ++j) {
        mn0[j] = 3.4e38f; sm0[j] = 0.0f;
        mn1[j] = 3.4e38f; sm1[j] = 0.0f;
    }
#pragma unroll
    for (int ch = 0; ch < NCH; ++ch)
#pragma unroll
        for (int j = 0; j < 4; ++j) {
            float s0 = (float)v0[ch][j];
            float s1 = (float)v1[ch][j];
            mn0[j] = fminf(mn0[j], s0); sm0[j] += s0;
            mn1[j] = fminf(mn1[j], s1); sm1[j] += s1;
        }

    float inv0[4], inv1[4];
#pragma unroll
    for (int j = 0; j < 4; ++j) {
        inv0[j] = __fdividef(1.0f, sm0[j] * (1.0f / 12.0f) - mn0[j]);
        inv1[j] = __fdividef(1.0f, sm1[j] * (1.0f / 12.0f) - mn1[j]);
    }

    float acc = 0.0f;
#pragma unroll
    for (int ch = 0; ch < NCH; ++ch)
#pragma unroll
        for (int j = 0; j < 4; ++j) {
            float e0 = __expf(-((float)v0[ch][j] - mn0[j]) * inv0[j]);
            float e1 = __expf(-((float)v1[ch][j] - mn1[j]) * inv1[j]);
            float df = e0 - e1;
            acc += df * df;
        }

#pragma unroll
    for (int off = 32; off > 0; off >>= 1)
        acc += __shfl_down(acc, off, 64);
    __shared__ float smem[4];
    int lane = threadIdx.x & 63, wv = threadIdx.x >> 6;
    if (lane == 0) smem[wv] = acc;
    __syncthreads();
    if (threadIdx.x == 0)
        partial[blockIdx.x] = smem[0] + smem[1] + smem[2] + smem[3];
}

// kred: sum 2048 partials, write the final scalar.
__global__ __launch_bounds__(256) void kred(const float* __restrict__ partial,
                                            float* __restrict__ out) {
    int tid = threadIdx.x;
    float acc = 0.0f;
#pragma unroll
    for (int k = 0; k < 8; ++k)
        acc += partial[tid + (k << 8)];
#pragma unroll
    for (int off = 32; off > 0; off >>= 1)
        acc += __shfl_down(acc, off, 64);
    __shared__ float smem[4];
    int lane = tid & 63, wv = tid >> 6;
    if (lane == 0) smem[wv] = acc;
    __syncthreads();
    if (tid == 0)
        out[0] = (smem[0] + smem[1] + smem[2] + smem[3])
               * (1.0f / (12.0f * (float)VOX));
}

__global__ void kdiag(float* out, float ws_mb) { out[0] = ws_mb; }

extern "C" void kernel_launch(void* const* d_in, const int* in_sizes, int n_in,
                              void* d_out, int out_size, void* d_ws, size_t ws_size,
                              hipStream_t stream) {
    const float* y_true = (const float*)d_in[0];
    const float* y_pred = (const float*)d_in[1];
    float* out = (float*)d_out;

    const size_t NEED = 2ull * IMGS * sizeof(_Float16) + 8192 + 64;  // ~96.2 MB
    if (ws_size < NEED) {
        kdiag<<<1, 1, 0, stream>>>(out, (float)(ws_size >> 20));
        return;
    }

    _Float16* S0      = (_Float16*)d_ws;            // ssd img0 (padded layout)
    _Float16* S1      = S0 + (size_t)IMGS;          // ssd img1
    float*    partial = (float*)(S1 + (size_t)IMGS);// 2048 floats

    f123<<<dim3(12 * 4 * 16, 2), 256, 0, stream>>>(y_true, y_pred, S0);
    kmse<<<VOX / 4 / 256, 256, 0, stream>>>(S0, S1, partial);
    kred<<<1, 256, 0, stream>>>(partial, out);
}

// Round 15
// 131.358 us; speedup vs baseline: 2.0380x; 1.1572x over previous
//
#include <hip/hip_runtime.h>

#define DIM   128
#define DMASK 127
#define PLANE (DIM * DIM)     // 16384
#define VOX   (1 << 21)       // 128^3
#define NCH   12

// De-aliased layout (validated r12: 199->142 us): channel stride 4MB+4KB,
// image stride +2KB more. Keeps the 24 stream bases off one channel slot.
#define CHS   (VOX + 2048)
#define IMGS  (NCH * CHS + 1024)

typedef __attribute__((ext_vector_type(2))) _Float16 half2v;
typedef __attribute__((ext_vector_type(4))) _Float16 half4v;

// Per-channel shift pairs (d,h,w) = 2*(one_hot_idx - 1); verified (absmax 0).
__constant__ int c_sd1[12] = { 0, 0, 0, 0, 0, 2, 2, 2, 0, 0, 0, 0};
__constant__ int c_sh1[12] = { 0,-2,-2, 0, 0, 0, 0, 0, 2, 2, 2, 2};
__constant__ int c_sw1[12] = {-2, 0, 0, 2, 2, 0, 0, 0, 0, 0, 0, 0};
__constant__ int c_sd2[12] = {-2,-2, 0,-2, 0, 0, 0, 0,-2, 0, 0, 2};
__constant__ int c_sh2[12] = { 0, 0, 0, 0,-2, 0,-2, 0, 0, 0, 0, 0};
__constant__ int c_sw2[12] = { 0, 0,-2, 0, 0,-2, 0, 2, 0,-2, 2, 0};

__device__ __forceinline__ int clamp7(int v) { return min(max(v, 0), DMASK); }

// F123 v5: WAVE-AUTONOMOUS. Each wave owns (ch, 8-row h-slice, 16-plane
// d-seg); W-box via lane shuffles (+/-1 lane = +/-2 cols), H-box via
// register sliding sums, D-box via register window. ZERO LDS, ZERO
// __syncthreads -> no barrier stalls (r12/r14: ~57% idle at 2 barriers/plane).
__global__ __launch_bounds__(256, 3) void f123(const float* __restrict__ img0,
                                               const float* __restrict__ img1,
                                               _Float16* __restrict__ Sall) {
    const float* img = blockIdx.y ? img1 : img0;
    _Float16* outS = Sall + (size_t)blockIdx.y * IMGS;
    const char* imgc = (const char*)img;

    int wid = (blockIdx.x << 2) + (threadIdx.x >> 6);  // 0..1535
    int ch = wid >> 7;                 // 12
    int hs = (wid >> 3) & 15;          // 16 h-slices of 8 rows
    int ds = wid & 7;                  // 8 d-segs of 16 planes
    int h0 = hs << 3;
    int d0 = ds << 4;
    int l  = threadIdx.x & 63;

    int sd1 = c_sd1[ch], sh1 = c_sh1[ch], sw1 = c_sw1[ch];
    int sd2 = c_sd2[ch], sh2 = c_sh2[ch], sw2 = c_sw2[ch];

    // wave-uniform row byte-offsets (double clamp composed), 12 rows
    int rowOffA[12], rowOffB[12];
#pragma unroll
    for (int r = 0; r < 12; ++r) {
        int hq = clamp7(h0 - 2 + r);
        rowOffA[r] = clamp7(hq + sh1) * (DIM * 4);
        rowOffB[r] = clamp7(hq + sh2) * (DIM * 4);
    }

    // per-lane column byte bases (float2 at cols 2l+sw, clamped to [0,126])
    int c2 = l << 1;
    int colA = min(max(c2 + sw1, 0), 126) * 4;
    int colB = min(max(c2 + sw2, 0), 126) * 4;
    bool fixAlo = (sw1 < 0) && (l == 0);   // need (v0,v0): a.y = a.x
    bool fixAhi = (sw1 > 0) && (l == 63);  // need (v127,v127): a.x = a.y
    bool fixBlo = (sw2 < 0) && (l == 0);
    bool fixBhi = (sw2 > 0) && (l == 63);

    float2 win[8];
    half2v hist[5][8];
#pragma unroll
    for (int k = 0; k < 8; ++k) {
        win[k].x = 0.0f; win[k].y = 0.0f;
#pragma unroll
        for (int s = 0; s < 5; ++s) hist[s][k] = half2v{(_Float16)0.0f, (_Float16)0.0f};
    }

    _Float16* dstBase = outS + (size_t)ch * CHS + h0 * DIM + c2;

    for (int oo = 0; oo < 4; ++oo) {
#pragma unroll
        for (int s5 = 0; s5 < 5; ++s5) {
            int it = oo * 5 + s5;
            int dp = clamp7(d0 - 2 + it);
            int pOffA = clamp7(dp + sd1) * (PLANE * 4);
            int pOffB = clamp7(dp + sd2) * (PLANE * 4);

            float tX[12], tY[12];
#pragma unroll
            for (int r = 0; r < 12; ++r) {
                float2 a = *(const float2*)(imgc + (pOffA + rowOffA[r] + colA));
                float2 b = *(const float2*)(imgc + (pOffB + rowOffB[r] + colB));
                a.y = fixAlo ? a.x : a.y;  a.x = fixAhi ? a.y : a.x;
                b.y = fixBlo ? b.x : b.y;  b.x = fixBhi ? b.y : b.x;
                float dx = a.x - b.x; dx *= dx;      // D2[2l]
                float dy = a.y - b.y; dy *= dy;      // D2[2l+1]
                float lx = __shfl_up(dx, 1, 64);     // D2[2l-2] (lane0: own dx = replicate OK)
                float ly = __shfl_up(dy, 1, 64);     // D2[2l-1]
                float rx = __shfl_down(dx, 1, 64);   // D2[2l+2]
                float ry = __shfl_down(dy, 1, 64);   // D2[2l+3] (lane63: own dy = replicate OK)
                ly = (l == 0)  ? dx : ly;            // D2[-1 -> 0]
                rx = (l == 63) ? dy : rx;            // D2[128 -> 127]
                tX[r] = lx + ly + dx + dy + rx;      // W-box(2l)
                tY[r] = ly + dx + dy + rx + ry;      // W-box(2l+1)
            }

            // H-box sliding 5-row sums + D-window update
            float sx = tX[0] + tX[1] + tX[2] + tX[3] + tX[4];
            float sy = tY[0] + tY[1] + tY[2] + tY[3] + tY[4];
            bool dowrite = (it >= 4);
            _Float16* dstD = dstBase + (size_t)(d0 + it - 4) * PLANE;
#pragma unroll
            for (int k = 0; k < 8; ++k) {
                half2v hv = { (_Float16)sx, (_Float16)sy };  // round first (validated)
                half2v old = hist[s5][k];
                win[k].x += (float)hv[0] - (float)old[0];
                win[k].y += (float)hv[1] - (float)old[1];
                hist[s5][k] = hv;
                if (dowrite) {
                    half2v ov = { (_Float16)win[k].x, (_Float16)win[k].y };
                    *(half2v*)(dstD + k * DIM) = ov;
                }
                if (k < 7) {
                    sx += tX[k + 5] - tX[k];
                    sy += tY[k + 5] - tY[k];
                }
            }
        }
    }
}

// kmse v6 (unchanged, validated r12): 4 vox/thread, 24 independent 8-B
// loads, all-register, no atomics, de-aliased CHS stride.
__global__ __launch_bounds__(256, 3) void kmse(const _Float16* __restrict__ S0,
                                               const _Float16* __restrict__ S1,
                                               float* __restrict__ partial) {
    int t = blockIdx.x * 256 + threadIdx.x;       // 2048 blocks

    half4v v0[NCH], v1[NCH];
#pragma unroll
    for (int ch = 0; ch < NCH; ++ch)
        v0[ch] = ((const half4v*)(S0 + (size_t)ch * CHS))[t];
#pragma unroll
    for (int ch = 0; ch < NCH; ++ch)
        v1[ch] = ((const half4v*)(S1 + (size_t)ch * CHS))[t];

    float mn0[4], sm0[4], mn1[4], sm1[4];
#pragma unroll
    for (int j = 0; j < 4; ++j) {
        mn0[j] = 3.4e38f; sm0[j] = 0.0f;
        mn1[j] = 3.4e38f; sm1[j] = 0.0f;
    }
#pragma unroll
    for (int ch = 0; ch < NCH; ++ch)
#pragma unroll
        for (int j = 0; j < 4; ++j) {
            float s0 = (float)v0[ch][j];
            float s1 = (float)v1[ch][j];
            mn0[j] = fminf(mn0[j], s0); sm0[j] += s0;
            mn1[j] = fminf(mn1[j], s1); sm1[j] += s1;
        }

    float inv0[4], inv1[4];
#pragma unroll
    for (int j = 0; j < 4; ++j) {
        inv0[j] = __fdividef(1.0f, sm0[j] * (1.0f / 12.0f) - mn0[j]);
        inv1[j] = __fdividef(1.0f, sm1[j] * (1.0f / 12.0f) - mn1[j]);
    }

    float acc = 0.0f;
#pragma unroll
    for (int ch = 0; ch < NCH; ++ch)
#pragma unroll
        for (int j = 0; j < 4; ++j) {
            float e0 = __expf(-((float)v0[ch][j] - mn0[j]) * inv0[j]);
            float e1 = __expf(-((float)v1[ch][j] - mn1[j]) * inv1[j]);
            float df = e0 - e1;
            acc += df * df;
        }

#pragma unroll
    for (int off = 32; off > 0; off >>= 1)
        acc += __shfl_down(acc, off, 64);
    __shared__ float smem[4];
    int lane = threadIdx.x & 63, wv = threadIdx.x >> 6;
    if (lane == 0) smem[wv] = acc;
    __syncthreads();
    if (threadIdx.x == 0)
        partial[blockIdx.x] = smem[0] + smem[1] + smem[2] + smem[3];
}

// kred: sum 2048 partials, write the final scalar.
__global__ __launch_bounds__(256) void kred(const float* __restrict__ partial,
                                            float* __restrict__ out) {
    int tid = threadIdx.x;
    float acc = 0.0f;
#pragma unroll
    for (int k = 0; k < 8; ++k)
        acc += partial[tid + (k << 8)];
#pragma unroll
    for (int off = 32; off > 0; off >>= 1)
        acc += __shfl_down(acc, off, 64);
    __shared__ float smem[4];
    int lane = tid & 63, wv = tid >> 6;
    if (lane == 0) smem[wv] = acc;
    __syncthreads();
    if (tid == 0)
        out[0] = (smem[0] + smem[1] + smem[2] + smem[3])
               * (1.0f / (12.0f * (float)VOX));
}

__global__ void kdiag(float* out, float ws_mb) { out[0] = ws_mb; }

extern "C" void kernel_launch(void* const* d_in, const int* in_sizes, int n_in,
                              void* d_out, int out_size, void* d_ws, size_t ws_size,
                              hipStream_t stream) {
    const float* y_true = (const float*)d_in[0];
    const float* y_pred = (const float*)d_in[1];
    float* out = (float*)d_out;

    const size_t NEED = 2ull * IMGS * sizeof(_Float16) + 8192 + 64;  // ~96.2 MB
    if (ws_size < NEED) {
        kdiag<<<1, 1, 0, stream>>>(out, (float)(ws_size >> 20));
        return;
    }

    _Float16* S0      = (_Float16*)d_ws;            // ssd img0 (padded layout)
    _Float16* S1      = S0 + (size_t)IMGS;          // ssd img1
    float*    partial = (float*)(S1 + (size_t)IMGS);// 2048 floats

    // 1536 wave-tasks per image (12 ch x 16 hslices x 8 dsegs), 4 waves/block
    f123<<<dim3(384, 2), 256, 0, stream>>>(y_true, y_pred, S0);
    kmse<<<VOX / 4 / 256, 256, 0, stream>>>(S0, S1, partial);
    kred<<<1, 256, 0, stream>>>(partial, out);
}